// Round 2
// baseline (114.206 us; speedup 1.0000x reference)
//
#include <hip/hip_runtime.h>
#include <math.h>

// Problem constants (from reference): B=8, L=2048, D=10
#define NB 8
#define L 2048
#define ND 10
#define NSLICE 32          // max j-slices per row = L/JS
#define JS 64              // j-slice size (inner loop length per block)
#define IT 256             // i-tile size (one thread per row)
#define LOG2E 1.4426950408889634f
#define CLIP2 (-28.853900817779268f)   // -20 * log2(e): clip applied in exp2 domain

__device__ __forceinline__ float softplus(float x) {
    // matches jax.nn.softplus within fp32 tolerance for the input ranges here
    return (x > 20.0f) ? x : log1pf(expf(x));
}

// Phase A: partial pairwise sums.
// grid = (144, NB). Block (k-tile, s-slice) decoded from blockIdx.x:
//   for i-tile k (0..7), j-slices s in [0, 4*(k+1)) cover j in [0, (k+1)*256).
// Each thread owns row i = k*256+tid, loops 64 j's, writes one partial:
//   part[b][s][i] = sum_{j in slice, j<i} g[ei,ej] * exp2(max(-b2[ei,ej]*(ti-tj), CLIP2))
__global__ __launch_bounds__(256) void hawkes_pairs(
    const float* __restrict__ tp, const int* __restrict__ et,
    const float* __restrict__ la, const float* __restrict__ lb,
    float* __restrict__ part)
{
    // tab[ej*ND + ei] = {alpha*beta, beta*log2e}  (transposed: uniform ej -> scalar base)
    __shared__ float2 tab[ND * ND];
    const int tid = threadIdx.x;
    if (tid < ND * ND) {
        const float a  = softplus(la[tid]);   // la row-major [ei][ej]
        const float bb = softplus(lb[tid]);
        const int ei = tid / ND, ej = tid % ND;
        tab[ej * ND + ei] = make_float2(a * bb, bb * LOG2E);
    }
    __syncthreads();

    const int bx = blockIdx.x;   // 0..143
    const int b  = blockIdx.y;
    int k = 7;                    // start(k) = 2k(k+1): 0,4,12,24,40,60,84,112
    while (k > 0 && bx < 2 * k * (k + 1)) --k;
    const int s = bx - 2 * k * (k + 1);
    const int i = k * IT + tid;
    const int jbase = s * JS;

    const float ti    = tp[b * L + i];
    const int   eiraw = et[b * L + i];
    const bool  vi    = eiraw >= 0;
    const int   ei    = vi ? eiraw : 0;

    const float* tpj = tp + b * L + jbase;  // wave-uniform addresses in the loop
    const int*   etj = et + b * L + jbase;

    float acc = 0.0f;
    #pragma unroll 8
    for (int jj = 0; jj < JS; ++jj) {
        const float tj    = tpj[jj];
        const int   ejraw = etj[jj];
        const int   ej    = (ejraw >= 0) ? ejraw : 0;
        const float2 p = tab[ej * ND + ei];
        const float x  = fmaxf(p.y * (tj - ti), CLIP2);  // = max(-b*(ti-tj), -20) in log2 domain
        const float e2 = exp2f(x);
        const bool ok = (ejraw >= 0) && ((jbase + jj) < i);
        acc += ok ? p.x * e2 : 0.0f;
    }
    part[(b * NSLICE + s) * L + i] = vi ? acc : 0.0f;
}

// Phase B: per-batch finalize. grid = (NB), 256 threads.
// out[b] = pos_b - (sum_d mu_d)*T_b - sum_j S(ej, T_b - t_j)
//   where S(c,dt) = sum_d alpha[d,c]*(1 - exp(-beta[d,c]*dt))
__global__ __launch_bounds__(256) void hawkes_final(
    const float* __restrict__ tp, const float* __restrict__ Tv,
    const float* __restrict__ mu_raw, const float* __restrict__ la,
    const float* __restrict__ lb, const int* __restrict__ et,
    const float* __restrict__ part, float* __restrict__ out)
{
    __shared__ float aT[ND * ND];   // aT[c*ND+d] = alpha[d][c]
    __shared__ float bT[ND * ND];   // bT[c*ND+d] = beta[d][c] * log2e
    __shared__ float mus[ND];
    __shared__ float rp[4], ri[4];
    __shared__ int   rn[4];

    const int tid = threadIdx.x;
    const int b = blockIdx.x;
    if (tid < ND * ND) {
        const int d = tid / ND, c = tid % ND;
        aT[c * ND + d] = softplus(la[tid]);
        bT[c * ND + d] = softplus(lb[tid]) * LOG2E;
    }
    if (tid < ND) mus[tid] = softplus(mu_raw[tid]);
    __syncthreads();

    float musum = 0.0f;
    #pragma unroll
    for (int d2 = 0; d2 < ND; ++d2) musum += mus[d2];
    const float Tb = Tv[b];

    float pos = 0.0f, integ = 0.0f;
    int nval = 0;
    for (int i = tid; i < L; i += 256) {
        const int   eraw = et[b * L + i];
        const float ti   = tp[b * L + i];
        const bool  v    = eraw >= 0;
        const int   es   = v ? eraw : 0;
        float lam = v ? mus[es] : 0.0f;
        const int ns = 4 * ((i >> 8) + 1);        // slices written for this row
        const float* pp = part + (b * NSLICE) * L + i;
        for (int s2 = 0; s2 < ns; ++s2) lam += pp[s2 * L];
        if (v) {
            pos += logf(fmaxf(lam, 1e-12f));
            nval++;
            const float dt = Tb - ti;
            float cs = 0.0f;
            #pragma unroll
            for (int d2 = 0; d2 < ND; ++d2)
                cs += aT[es * ND + d2] * (1.0f - exp2f(-bT[es * ND + d2] * dt));
            integ += cs;
        }
    }
    #pragma unroll
    for (int off = 32; off > 0; off >>= 1) {
        pos   += __shfl_down(pos, off);
        integ += __shfl_down(integ, off);
        nval  += __shfl_down(nval, off);
    }
    const int wid = tid >> 6;
    if ((tid & 63) == 0) { rp[wid] = pos; ri[wid] = integ; rn[wid] = nval; }
    __syncthreads();
    if (tid == 0) {
        const float P = rp[0] + rp[1] + rp[2] + rp[3];
        const float I = ri[0] + ri[1] + ri[2] + ri[3];
        const int   N = rn[0] + rn[1] + rn[2] + rn[3];
        out[b] = ((N == 0) ? 0.0f : P) - (musum * Tb + I);
    }
}

extern "C" void kernel_launch(void* const* d_in, const int* in_sizes, int n_in,
                              void* d_out, int out_size, void* d_ws, size_t ws_size,
                              hipStream_t stream) {
    const float* tp = (const float*)d_in[0];   // time_points [B][L]
    const float* Tv = (const float*)d_in[1];   // T [B]
    const float* mu = (const float*)d_in[2];   // mu_raw [D]
    const float* la = (const float*)d_in[3];   // log_alpha [D][D]
    const float* lb = (const float*)d_in[4];   // log_beta [D][D]
    const int*   et = (const int*)d_in[5];     // event_types [B][L]
    float* part = (float*)d_ws;                // [NB][NSLICE][L] f32 = 2 MB
    float* out  = (float*)d_out;               // [NB] f32

    hipLaunchKernelGGL(hawkes_pairs, dim3(144, NB), dim3(256), 0, stream,
                       tp, et, la, lb, part);
    hipLaunchKernelGGL(hawkes_final, dim3(NB), dim3(256), 0, stream,
                       tp, Tv, mu, la, lb, et, part, out);
}

// Round 3
// 80.677 us; speedup vs baseline: 1.4156x; 1.4156x over previous
//
#include <hip/hip_runtime.h>
#include <math.h>

// Problem constants (from reference): B=8, L=2048, D=10
#define NB 8
#define L 2048
#define ND 10
#define NSLICE 32          // j-slices per row = L/JS
#define JS 64              // j-slice size (inner loop length per block)
#define IT 256             // i-tile size (one thread per row)
#define TABR 11            // 10 event types + a zero row for invalid ej
#define LOG2E 1.4426950408889634f
#define CLIP2 (-28.853900817779268f)   // -20 * log2(e): clip applied in exp2 domain

__device__ __forceinline__ float softplus(float x) {
    return (x > 20.0f) ? x : log1pf(expf(x));
}

// ---------------- Phase A: partial pairwise sums ----------------
// grid = (144, NB). Block (k,s) decoded from blockIdx.x: tile k has 4(k+1)
// slices, start(k) = 2k(k+1). Thread owns row i = k*256+tid, loops 64 j's:
//   part[b][s][i] = sum_{j in slice, j<i} ab[ei,ej]*exp2(max(blog2e[ei,ej]*(tj-ti), CLIP2))
// Invalid ej -> table row 10 (zeros) -> term 0, no mask needed in hot loop.
__global__ __launch_bounds__(256) void hawkes_pairs(
    const float* __restrict__ tp, const int* __restrict__ et,
    const float* __restrict__ la, const float* __restrict__ lb,
    float* __restrict__ part)
{
    __shared__ float2 tab[TABR * ND];  // [ej][ei] = {alpha*beta, beta*log2e}
    __shared__ int2   js[JS];          // {bitcast(tj), ej_safe * 80 (byte off)}
    const int tid = threadIdx.x;

    if (tid < ND * ND) {
        const float a  = softplus(la[tid]);   // la row-major [ei][ej]
        const float bb = softplus(lb[tid]);
        const int ei = tid / ND, ej = tid % ND;
        tab[ej * ND + ei] = make_float2(a * bb, bb * LOG2E);
    } else if (tid < ND * ND + ND) {
        tab[ND * ND + (tid - ND * ND)] = make_float2(0.0f, 0.0f);  // zero row
    }

    const int bx = blockIdx.x;   // 0..143
    const int b  = blockIdx.y;
    int k = 7;                    // start(k) = 2k(k+1): 0,4,12,24,40,60,84,112
    while (k > 0 && bx < 2 * k * (k + 1)) --k;
    const int s = bx - 2 * k * (k + 1);
    const int jbase = s * JS;
    const int i = k * IT + tid;

    if (tid < JS) {
        const int   ejraw = et[b * L + jbase + tid];
        const float tj    = tp[b * L + jbase + tid];
        const int   ejs   = (ejraw >= 0) ? ejraw : ND;   // ND -> zero row
        js[tid] = make_int2(__float_as_int(tj), ejs * (int)(ND * sizeof(float2)));
    }
    __syncthreads();

    const float ti    = tp[b * L + i];
    const int   eiraw = et[b * L + i];
    const bool  vi    = eiraw >= 0;
    const char* tabp  = (const char*)tab + (vi ? eiraw : 0) * (int)sizeof(float2);

    float acc = 0.0f;
    if (jbase < k * IT) {
        // strictly-lower slice: j < i holds for every lane -> no mask at all
        #pragma unroll 16
        for (int jj = 0; jj < JS; ++jj) {
            const int2   q = js[jj];
            const float2 p = *(const float2*)(tabp + q.y);
            const float  x = fmaxf(p.y * (__int_as_float(q.x) - ti), CLIP2);
            acc = fmaf(p.x, exp2f(x), acc);
        }
    } else {
        // diagonal slice: enforce j < i per lane
        #pragma unroll 16
        for (int jj = 0; jj < JS; ++jj) {
            const int2   q = js[jj];
            const float2 p = *(const float2*)(tabp + q.y);
            const float  x = fmaxf(p.y * (__int_as_float(q.x) - ti), CLIP2);
            const float  w = (jbase + jj < i) ? p.x : 0.0f;
            acc = fmaf(w, exp2f(x), acc);
        }
    }
    part[(b * NSLICE + s) * L + i] = vi ? acc : 0.0f;
}

// ---------------- Phase B1: per-row finalize ----------------
// grid = (8 tiles, NB), 256 threads, ONE row per thread.
// rowred[b*8+tile] = {sum logl, sum integral-contrib, n_valid, 0}
__global__ __launch_bounds__(256) void hawkes_row(
    const float* __restrict__ tp, const float* __restrict__ Tv,
    const float* __restrict__ mu_raw, const float* __restrict__ la,
    const float* __restrict__ lb, const int* __restrict__ et,
    const float* __restrict__ part, float4* __restrict__ rowred)
{
    __shared__ float aT[ND * ND];   // aT[c*ND+d] = alpha[d][c]
    __shared__ float bT[ND * ND];   // bT[c*ND+d] = beta[d][c] * log2e
    __shared__ float mus[ND];
    __shared__ float rp[4], ri[4];
    __shared__ int   rn[4];

    const int tid  = threadIdx.x;
    const int tile = blockIdx.x;
    const int b    = blockIdx.y;
    if (tid < ND * ND) {
        const int d = tid / ND, c = tid % ND;
        aT[c * ND + d] = softplus(la[tid]);
        bT[c * ND + d] = softplus(lb[tid]) * LOG2E;
    }
    if (tid < ND) mus[tid] = softplus(mu_raw[tid]);
    __syncthreads();

    const int   i    = tile * IT + tid;
    const int   eraw = et[b * L + i];
    const float ti   = tp[b * L + i];
    const bool  v    = eraw >= 0;
    const int   es   = v ? eraw : 0;
    const int   ns   = 4 * (tile + 1);           // slices written for this tile
    const float* pp  = part + b * NSLICE * L + i;

    float lam = v ? mus[es] : 0.0f;
    #pragma unroll
    for (int s0 = 0; s0 < NSLICE; s0 += 4) {     // uniform branch per 4-chunk,
        if (s0 < ns) {                            // loads batch-issued inside
            lam += pp[(s0 + 0) * L];
            lam += pp[(s0 + 1) * L];
            lam += pp[(s0 + 2) * L];
            lam += pp[(s0 + 3) * L];
        }
    }

    float pos = 0.0f, integ = 0.0f;
    int nv = 0;
    if (v) {
        pos = logf(fmaxf(lam, 1e-12f));
        nv = 1;
        const float dt = Tv[b] - ti;
        #pragma unroll
        for (int d2 = 0; d2 < ND; ++d2)
            integ += aT[es * ND + d2] * (1.0f - exp2f(-bT[es * ND + d2] * dt));
    }
    #pragma unroll
    for (int off = 32; off > 0; off >>= 1) {
        pos   += __shfl_down(pos, off);
        integ += __shfl_down(integ, off);
        nv    += __shfl_down(nv, off);
    }
    const int wid = tid >> 6;
    if ((tid & 63) == 0) { rp[wid] = pos; ri[wid] = integ; rn[wid] = nv; }
    __syncthreads();
    if (tid == 0) {
        rowred[b * 8 + tile] = make_float4(rp[0] + rp[1] + rp[2] + rp[3],
                                           ri[0] + ri[1] + ri[2] + ri[3],
                                           (float)(rn[0] + rn[1] + rn[2] + rn[3]),
                                           0.0f);
    }
}

// ---------------- Phase B2: tiny final reduce ----------------
// 1 block, 64 threads; lane b < NB produces out[b].
__global__ void hawkes_out(
    const float* __restrict__ Tv, const float* __restrict__ mu_raw,
    const float4* __restrict__ rowred, float* __restrict__ out)
{
    const int b = threadIdx.x;
    float musum = 0.0f;
    #pragma unroll
    for (int d = 0; d < ND; ++d) musum += softplus(mu_raw[d]);
    if (b < NB) {
        float P = 0.0f, I = 0.0f;
        int   N = 0;
        #pragma unroll
        for (int t = 0; t < 8; ++t) {
            const float4 r = rowred[b * 8 + t];
            P += r.x; I += r.y; N += (int)r.z;
        }
        out[b] = ((N == 0) ? 0.0f : P) - (musum * Tv[b] + I);
    }
}

extern "C" void kernel_launch(void* const* d_in, const int* in_sizes, int n_in,
                              void* d_out, int out_size, void* d_ws, size_t ws_size,
                              hipStream_t stream) {
    const float* tp = (const float*)d_in[0];   // time_points [B][L]
    const float* Tv = (const float*)d_in[1];   // T [B]
    const float* mu = (const float*)d_in[2];   // mu_raw [D]
    const float* la = (const float*)d_in[3];   // log_alpha [D][D]
    const float* lb = (const float*)d_in[4];   // log_beta [D][D]
    const int*   et = (const int*)d_in[5];     // event_types [B][L]
    float* part = (float*)d_ws;                // [NB][NSLICE][L] f32 = 2 MB
    // rowred lives in a provably-untouched hole of `part`:
    // cells (b=0, s=31, i<1792) are written only by tile k=7 (i>=1792) and
    // read only at i>=1792 -> the first 256 floats of that strip are free.
    float4* rowred = (float4*)(part + (0 * NSLICE + 31) * L);   // 64 x float4
    float* out = (float*)d_out;                // [NB] f32

    hipLaunchKernelGGL(hawkes_pairs, dim3(144, NB), dim3(256), 0, stream,
                       tp, et, la, lb, part);
    hipLaunchKernelGGL(hawkes_row, dim3(8, NB), dim3(256), 0, stream,
                       tp, Tv, mu, la, lb, et, part, rowred);
    hipLaunchKernelGGL(hawkes_out, dim3(1), dim3(64), 0, stream,
                       Tv, mu, rowred, out);
}

// Round 5
// 79.371 us; speedup vs baseline: 1.4389x; 1.0165x over previous
//
#include <hip/hip_runtime.h>
#include <math.h>

// Problem constants (from reference): B=8, L=2048, D=10
#define NB 8
#define L 2048
#define ND 10
#define NSLICE 32          // j-slices per row = L/JS
#define JS 64              // j-slice size (inner loop length per block)
#define IT 256             // i-tile size (one thread per row)
#define TABR 11            // 10 event types + a zero row for invalid ej
#define LOG2E 1.4426950408889634f
#define LN2   0.6931471805599453f
#define CLIP2 (-28.853900817779268f)   // -20 * log2(e): clip applied in exp2 domain

// Fast transcendentals: bare v_exp_f32 / v_log_f32 (1-ulp), skipping the
// OCML range-checked expansion. NOTE (round-4 lesson): v_exp_f32 is 2^x and
// v_log_f32 is LOG2(x) — natural log needs the ln2 scale.
#if __has_builtin(__builtin_amdgcn_exp2f)
#define EXP2F(x) __builtin_amdgcn_exp2f(x)
#else
#define EXP2F(x) exp2f(x)
#endif
#if __has_builtin(__builtin_amdgcn_logf)
#define LOGNF(x) (LN2 * __builtin_amdgcn_logf(x))   // ln(x) = ln2 * log2(x)
#else
#define LOGNF(x) logf(x)
#endif

__device__ __forceinline__ float softplus(float x) {
    return (x > 20.0f) ? x : log1pf(expf(x));   // cold path only (210 calls)
}

// ---------------- Phase A: partial pairwise sums ----------------
// grid = (144, NB). Block (k,s) decoded from blockIdx.x: tile k has 4(k+1)
// slices, start(k) = 2k(k+1). Thread owns row i = k*256+tid, loops 64 j's:
//   part[b][s][i] = sum_{j in slice, j<i} ab[ei,ej]*exp2(max(blog2e[ei,ej]*(tj-ti), CLIP2))
// Invalid ej -> table row 10 (zeros) -> term 0, no mask needed in hot loop.
__global__ __launch_bounds__(256) void hawkes_pairs(
    const float* __restrict__ tp, const int* __restrict__ et,
    const float* __restrict__ la, const float* __restrict__ lb,
    float* __restrict__ part)
{
    __shared__ float2 tab[TABR * ND];  // [ej][ei] = {alpha*beta, beta*log2e}
    __shared__ int2   js[JS];          // {bitcast(tj), ej_safe * 80 (byte off)}
    const int tid = threadIdx.x;

    if (tid < ND * ND) {
        const float a  = softplus(la[tid]);   // la row-major [ei][ej]
        const float bb = softplus(lb[tid]);
        const int ei = tid / ND, ej = tid % ND;
        tab[ej * ND + ei] = make_float2(a * bb, bb * LOG2E);
    } else if (tid < ND * ND + ND) {
        tab[ND * ND + (tid - ND * ND)] = make_float2(0.0f, 0.0f);  // zero row
    }

    const int bx = blockIdx.x;   // 0..143
    const int b  = blockIdx.y;
    int k = 7;                    // start(k) = 2k(k+1): 0,4,12,24,40,60,84,112
    while (k > 0 && bx < 2 * k * (k + 1)) --k;
    const int s = bx - 2 * k * (k + 1);
    const int jbase = s * JS;
    const int i = k * IT + tid;

    if (tid < JS) {
        const int   ejraw = et[b * L + jbase + tid];
        const float tj    = tp[b * L + jbase + tid];
        const int   ejs   = (ejraw >= 0) ? ejraw : ND;   // ND -> zero row
        js[tid] = make_int2(__float_as_int(tj), ejs * (int)(ND * sizeof(float2)));
    }
    __syncthreads();

    const float ti    = tp[b * L + i];
    const int   eiraw = et[b * L + i];
    const bool  vi    = eiraw >= 0;
    const char* tabp  = (const char*)tab + (vi ? eiraw : 0) * (int)sizeof(float2);

    float acc = 0.0f;
    if (jbase < k * IT) {
        // strictly-lower slice: j < i holds for every lane -> no mask at all
        #pragma unroll 16
        for (int jj = 0; jj < JS; ++jj) {
            const int2   q = js[jj];
            const float2 p = *(const float2*)(tabp + q.y);
            const float  x = fmaxf(p.y * (__int_as_float(q.x) - ti), CLIP2);
            acc = fmaf(p.x, EXP2F(x), acc);
        }
    } else {
        // diagonal slice: enforce j < i per lane
        #pragma unroll 16
        for (int jj = 0; jj < JS; ++jj) {
            const int2   q = js[jj];
            const float2 p = *(const float2*)(tabp + q.y);
            const float  x = fmaxf(p.y * (__int_as_float(q.x) - ti), CLIP2);
            const float  w = (jbase + jj < i) ? p.x : 0.0f;
            acc = fmaf(w, EXP2F(x), acc);
        }
    }
    part[(b * NSLICE + s) * L + i] = vi ? acc : 0.0f;
}

// ---------------- Phase B1: per-row finalize ----------------
// grid = (8 tiles, NB), 256 threads, ONE row per thread.
// rowred[b*8+tile] = {sum logl, sum integral-contrib, n_valid, 0}
__global__ __launch_bounds__(256) void hawkes_row(
    const float* __restrict__ tp, const float* __restrict__ Tv,
    const float* __restrict__ mu_raw, const float* __restrict__ la,
    const float* __restrict__ lb, const int* __restrict__ et,
    const float* __restrict__ part, float4* __restrict__ rowred)
{
    __shared__ float aT[ND * ND];   // aT[c*ND+d] = alpha[d][c]
    __shared__ float bT[ND * ND];   // bT[c*ND+d] = beta[d][c] * log2e
    __shared__ float mus[ND];
    __shared__ float rp[4], ri[4];
    __shared__ int   rn[4];

    const int tid  = threadIdx.x;
    const int tile = blockIdx.x;
    const int b    = blockIdx.y;
    if (tid < ND * ND) {
        const int d = tid / ND, c = tid % ND;
        aT[c * ND + d] = softplus(la[tid]);
        bT[c * ND + d] = softplus(lb[tid]) * LOG2E;
    }
    if (tid < ND) mus[tid] = softplus(mu_raw[tid]);
    __syncthreads();

    const int   i    = tile * IT + tid;
    const int   eraw = et[b * L + i];
    const float ti   = tp[b * L + i];
    const bool  v    = eraw >= 0;
    const int   es   = v ? eraw : 0;
    const int   ns   = 4 * (tile + 1);           // slices written for this tile
    const float* pp  = part + b * NSLICE * L + i;

    float lam = v ? mus[es] : 0.0f;
    #pragma unroll
    for (int s0 = 0; s0 < NSLICE; s0 += 4) {     // uniform branch per 4-chunk,
        if (s0 < ns) {                            // loads batch-issued inside
            lam += pp[(s0 + 0) * L];
            lam += pp[(s0 + 1) * L];
            lam += pp[(s0 + 2) * L];
            lam += pp[(s0 + 3) * L];
        }
    }

    float pos = 0.0f, integ = 0.0f;
    int nv = 0;
    if (v) {
        pos = LOGNF(fmaxf(lam, 1e-12f));
        nv = 1;
        const float dt = Tv[b] - ti;
        #pragma unroll
        for (int d2 = 0; d2 < ND; ++d2)
            integ += aT[es * ND + d2] * (1.0f - EXP2F(-bT[es * ND + d2] * dt));
    }
    #pragma unroll
    for (int off = 32; off > 0; off >>= 1) {
        pos   += __shfl_down(pos, off);
        integ += __shfl_down(integ, off);
        nv    += __shfl_down(nv, off);
    }
    const int wid = tid >> 6;
    if ((tid & 63) == 0) { rp[wid] = pos; ri[wid] = integ; rn[wid] = nv; }
    __syncthreads();
    if (tid == 0) {
        rowred[b * 8 + tile] = make_float4(rp[0] + rp[1] + rp[2] + rp[3],
                                           ri[0] + ri[1] + ri[2] + ri[3],
                                           (float)(rn[0] + rn[1] + rn[2] + rn[3]),
                                           0.0f);
    }
}

// ---------------- Phase B2: tiny final reduce ----------------
// 1 block, 64 threads; lane b < NB produces out[b].
__global__ void hawkes_out(
    const float* __restrict__ Tv, const float* __restrict__ mu_raw,
    const float4* __restrict__ rowred, float* __restrict__ out)
{
    const int b = threadIdx.x;
    float musum = 0.0f;
    #pragma unroll
    for (int d = 0; d < ND; ++d) musum += softplus(mu_raw[d]);
    if (b < NB) {
        float P = 0.0f, I = 0.0f;
        int   N = 0;
        #pragma unroll
        for (int t = 0; t < 8; ++t) {
            const float4 r = rowred[b * 8 + t];
            P += r.x; I += r.y; N += (int)r.z;
        }
        out[b] = ((N == 0) ? 0.0f : P) - (musum * Tv[b] + I);
    }
}

extern "C" void kernel_launch(void* const* d_in, const int* in_sizes, int n_in,
                              void* d_out, int out_size, void* d_ws, size_t ws_size,
                              hipStream_t stream) {
    const float* tp = (const float*)d_in[0];   // time_points [B][L]
    const float* Tv = (const float*)d_in[1];   // T [B]
    const float* mu = (const float*)d_in[2];   // mu_raw [D]
    const float* la = (const float*)d_in[3];   // log_alpha [D][D]
    const float* lb = (const float*)d_in[4];   // log_beta [D][D]
    const int*   et = (const int*)d_in[5];     // event_types [B][L]
    float* part = (float*)d_ws;                // [NB][NSLICE][L] f32 = 2 MB
    // rowred lives in a provably-untouched hole of `part`:
    // cells (b=0, s=31, i<1792) are written only by tile k=7 (i>=1792) and
    // read only at i>=1792 -> the first 256 floats of that strip are free.
    float4* rowred = (float4*)(part + (0 * NSLICE + 31) * L);   // 64 x float4
    float* out = (float*)d_out;                // [NB] f32

    hipLaunchKernelGGL(hawkes_pairs, dim3(144, NB), dim3(256), 0, stream,
                       tp, et, la, lb, part);
    hipLaunchKernelGGL(hawkes_row, dim3(8, NB), dim3(256), 0, stream,
                       tp, Tv, mu, la, lb, et, part, rowred);
    hipLaunchKernelGGL(hawkes_out, dim3(1), dim3(64), 0, stream,
                       Tv, mu, rowred, out);
}